// Round 3
// baseline (1551.090 us; speedup 1.0000x reference)
//
#include <hip/hip_runtime.h>

// out[i*2+0] = vertex_attr[i*2+0]
// out[i*2+1] = vertex_attr[i*2+0] * segment_sum(edge_attr, dst)[i]
//
// Strategy: per-XCD private accumulator replicas. Workgroup-scope float
// atomics execute inside the local (per-XCD) L2 — coherent for every block
// on that XCD — instead of paying one fabric transaction per atomic like
// device-scope atomicAdd does (round-1 counters: WRITE_SIZE = 32M x 32B = 1GB).
// Replica selected by the real hardware XCC id (s_getreg HW_REG_XCC_ID),
// so correctness does NOT depend on the blockIdx->XCD mapping.

#define NXCD 8

typedef int   iv4 __attribute__((ext_vector_type(4)));
typedef float fv4 __attribute__((ext_vector_type(4)));

__device__ __forceinline__ unsigned xcc_id() {
    unsigned x;
    asm volatile("s_getreg_b32 %0, hwreg(HW_REG_XCC_ID)" : "=s"(x));
    return x & (NXCD - 1);
}

__device__ __forceinline__ void l2_atomic_add(float* p, float v) {
    __hip_atomic_fetch_add(p, v, __ATOMIC_RELAXED, __HIP_MEMORY_SCOPE_WORKGROUP);
}

__global__ void scatter_add_xcd(const int* __restrict__ dst,
                                const float* __restrict__ w,
                                float* __restrict__ rep,   // [NXCD][n_v]
                                int n_v, int n_e) {
    const unsigned xcc = xcc_id();
    float* __restrict__ r = rep + (size_t)xcc * (size_t)n_v;
    const int tid = blockIdx.x * blockDim.x + threadIdx.x;
    const int stride = gridDim.x * blockDim.x;
    const int n_e4 = n_e >> 2;
    const iv4* __restrict__ d4 = (const iv4*)dst;
    const fv4* __restrict__ w4 = (const fv4*)w;
    for (int j = tid; j < n_e4; j += stride) {
        iv4 d = __builtin_nontemporal_load(&d4[j]);     // keep L2 for the accumulator
        fv4 v = __builtin_nontemporal_load(&w4[j]);
        l2_atomic_add(&r[d.x], v.x);
        l2_atomic_add(&r[d.y], v.y);
        l2_atomic_add(&r[d.z], v.z);
        l2_atomic_add(&r[d.w], v.w);
    }
    for (int j = (n_e4 << 2) + tid; j < n_e; j += stride) {
        l2_atomic_add(&r[dst[j]], w[j]);
    }
}

// Fallback (ws too small for replicas): device-scope atomics into one array.
__global__ void scatter_add_dev(const int* __restrict__ dst,
                                const float* __restrict__ w,
                                float* __restrict__ cbar, int n_e) {
    const int tid = blockIdx.x * blockDim.x + threadIdx.x;
    const int stride = gridDim.x * blockDim.x;
    const int n_e4 = n_e >> 2;
    const iv4* __restrict__ d4 = (const iv4*)dst;
    const fv4* __restrict__ w4 = (const fv4*)w;
    for (int j = tid; j < n_e4; j += stride) {
        iv4 d = d4[j];
        fv4 v = w4[j];
        atomicAdd(&cbar[d.x], v.x);
        atomicAdd(&cbar[d.y], v.y);
        atomicAdd(&cbar[d.z], v.z);
        atomicAdd(&cbar[d.w], v.w);
    }
    for (int j = (n_e4 << 2) + tid; j < n_e; j += stride)
        atomicAdd(&cbar[dst[j]], w[j]);
}

// Sum the NXCD replicas and produce out[i] = {b_i, b_i * cbar_i}.
__global__ void finalize_reduce(const float* __restrict__ va,
                                const float* __restrict__ rep,
                                float* __restrict__ out, int n_v) {
    const int tid = blockIdx.x * blockDim.x + threadIdx.x;
    const int stride = gridDim.x * blockDim.x;
    const int n_q = n_v >> 2;                  // quads of vertices
    for (int q = tid; q < n_q; q += stride) {
        fv4 s = (fv4){0.f, 0.f, 0.f, 0.f};
        for (int k = 0; k < NXCD; ++k) {
            const fv4* rk = (const fv4*)(rep + (size_t)k * (size_t)n_v);
            fv4 t = rk[q];
            s += t;
        }
        fv4 a0 = ((const fv4*)va)[2 * q];      // b0 c0 b1 c1
        fv4 a1 = ((const fv4*)va)[2 * q + 1];  // b2 c2 b3 c3
        fv4 o0 = (fv4){a0.x, a0.x * s.x, a0.z, a0.z * s.y};
        fv4 o1 = (fv4){a1.x, a1.x * s.z, a1.z, a1.z * s.w};
        ((fv4*)out)[2 * q]     = o0;
        ((fv4*)out)[2 * q + 1] = o1;
    }
    for (int v = (n_q << 2) + tid; v < n_v; v += stride) {
        float s = 0.f;
        for (int k = 0; k < NXCD; ++k) s += rep[(size_t)k * n_v + v];
        float b = va[2 * v];
        out[2 * v] = b;
        out[2 * v + 1] = b * s;
    }
}

__global__ void finalize_single(const float* __restrict__ va,
                                const float* __restrict__ cbar,
                                float* __restrict__ out, int n_v) {
    const int tid = blockIdx.x * blockDim.x + threadIdx.x;
    const int stride = gridDim.x * blockDim.x;
    for (int i = tid; i < n_v; i += stride) {
        float b = va[2 * i];
        float2 o; o.x = b; o.y = b * cbar[i];
        ((float2*)out)[i] = o;
    }
}

extern "C" void kernel_launch(void* const* d_in, const int* in_sizes, int n_in,
                              void* d_out, int out_size, void* d_ws, size_t ws_size,
                              hipStream_t stream) {
    const float* vertex_attr = (const float*)d_in[0];   // (n_v, 2) f32
    const int*   edgeij      = (const int*)d_in[1];     // (2, n_e) int32
    const float* edge_attr   = (const float*)d_in[2];   // (n_e, 1) f32

    const int n_vertices = in_sizes[0] / 2;
    const int n_edges    = in_sizes[2];
    const int* dst = edgeij + n_edges;                  // row 1 of (2, n_e)

    const size_t rep_bytes = (size_t)NXCD * (size_t)n_vertices * sizeof(float);
    float* ws = (float*)d_ws;

    if (ws_size >= rep_bytes) {
        // Fast path: per-XCD replicas + workgroup-scope (L2-local) atomics.
        (void)hipMemsetAsync(ws, 0, rep_bytes, stream);
        {
            const int n_e4 = n_edges >> 2;
            int threads = 256;
            int blocks = (n_e4 + threads - 1) / threads;
            if (blocks > 4096) blocks = 4096;
            if (blocks < 1) blocks = 1;
            scatter_add_xcd<<<blocks, threads, 0, stream>>>(dst, edge_attr, ws,
                                                            n_vertices, n_edges);
        }
        {
            int threads = 256;
            int n_q = n_vertices >> 2;
            int blocks = (n_q + threads - 1) / threads;
            if (blocks > 2048) blocks = 2048;
            if (blocks < 1) blocks = 1;
            finalize_reduce<<<blocks, threads, 0, stream>>>(vertex_attr, ws,
                                                            (float*)d_out, n_vertices);
        }
    } else {
        // Fallback: single accumulator, device-scope atomics (round-1 path).
        (void)hipMemsetAsync(ws, 0, (size_t)n_vertices * sizeof(float), stream);
        {
            const int n_e4 = n_edges >> 2;
            int threads = 256;
            int blocks = (n_e4 + threads - 1) / threads;
            if (blocks > 4096) blocks = 4096;
            if (blocks < 1) blocks = 1;
            scatter_add_dev<<<blocks, threads, 0, stream>>>(dst, edge_attr, ws, n_edges);
        }
        {
            int threads = 256;
            int blocks = (n_vertices + threads - 1) / threads;
            if (blocks > 2048) blocks = 2048;
            finalize_single<<<blocks, threads, 0, stream>>>(vertex_attr, ws,
                                                            (float*)d_out, n_vertices);
        }
    }
}

// Round 4
// 598.769 us; speedup vs baseline: 2.5905x; 2.5905x over previous
//
#include <hip/hip_runtime.h>

// out[i*2+0] = vertex_attr[i*2+0]
// out[i*2+1] = vertex_attr[i*2+0] * segment_sum(edge_attr, dst)[i]
//
// Round-3 lesson: f32 global atomics (any scope) execute memory-side at
// ~1/cycle/XCD (WRITE_SIZE = 32B/atomic, 21 G/s). So: NO per-edge global
// atomics. Instead: bucket edges by dst>>11 (512 buckets x 2048 vertices),
// then one workgroup per bucket accumulates in LDS (ds_add_f32) and writes
// its vertex range exclusively with plain stores.
//
// Edge record packed to ONE u32: val f32 rounded to 21-bit mantissa (rel err
// 2^-12) in the high bits | 11-bit in-bucket vertex index in the low bits.

#define VB_SHIFT 11
#define VB       (1 << VB_SHIFT)   // 2048 vertices per bucket
#define NBUCKETS 512               // covers up to 1,048,576 vertices
#define NB_HIST  512               // blocks in hist/scatter (== scan width)
#define TPB_BIN  512

typedef int   iv4 __attribute__((ext_vector_type(4)));
typedef float fv4 __attribute__((ext_vector_type(4)));

__device__ __forceinline__ unsigned pack_edge(int d, float v) {
    unsigned vb = __float_as_uint(v);
    vb = (vb + 0x400u) & 0xFFFFF800u;          // round mantissa to 21 bits
    return vb | (unsigned)(d & (VB - 1));
}

// ---------------- pass 1a: per-block bucket histogram ----------------
__global__ void hist_kernel(const int* __restrict__ dst,
                            int* __restrict__ hist, int n_e) {
    __shared__ int h[NBUCKETS];
    for (int i = threadIdx.x; i < NBUCKETS; i += blockDim.x) h[i] = 0;
    __syncthreads();
    const int span = (((n_e + (int)gridDim.x - 1) / (int)gridDim.x) + 3) & ~3;
    const int lo = blockIdx.x * span;
    const int hi = min(lo + span, n_e);
    const iv4* __restrict__ d4 = (const iv4*)dst;
    for (int j = (lo >> 2) + (int)threadIdx.x; j < (hi >> 2); j += blockDim.x) {
        iv4 d = d4[j];
        atomicAdd(&h[d.x >> VB_SHIFT], 1);
        atomicAdd(&h[d.y >> VB_SHIFT], 1);
        atomicAdd(&h[d.z >> VB_SHIFT], 1);
        atomicAdd(&h[d.w >> VB_SHIFT], 1);
    }
    for (int j = max(lo, (hi >> 2) << 2) + (int)threadIdx.x; j < hi; j += blockDim.x)
        atomicAdd(&h[dst[j] >> VB_SHIFT], 1);
    __syncthreads();
    for (int i = threadIdx.x; i < NBUCKETS; i += blockDim.x)
        hist[(size_t)i * gridDim.x + blockIdx.x] = h[i];
}

// ---------------- pass 1b: scans ----------------
// exclusive scan within each bucket row (length NB_HIST); row total out.
__global__ void scan_rows(int* __restrict__ hist, int* __restrict__ rowtot) {
    __shared__ int s[NB_HIST];
    const int r = blockIdx.x, t = threadIdx.x;
    int* row = hist + (size_t)r * NB_HIST;
    int x = row[t];
    s[t] = x;
    __syncthreads();
    for (int off = 1; off < NB_HIST; off <<= 1) {
        int add = (t >= off) ? s[t - off] : 0;
        __syncthreads();
        s[t] += add;
        __syncthreads();
    }
    row[t] = s[t] - x;                         // exclusive within row
    if (t == NB_HIST - 1) rowtot[r] = s[t];
}

// exclusive scan across bucket totals; bases[NBUCKETS] = grand total.
__global__ void scan_bases(const int* __restrict__ rowtot, int* __restrict__ bases) {
    __shared__ int s[NBUCKETS];
    const int t = threadIdx.x;
    int x = rowtot[t];
    s[t] = x;
    __syncthreads();
    for (int off = 1; off < NBUCKETS; off <<= 1) {
        int add = (t >= off) ? s[t - off] : 0;
        __syncthreads();
        s[t] += add;
        __syncthreads();
    }
    bases[t] = s[t] - x;
    if (t == NBUCKETS - 1) bases[NBUCKETS] = s[t];
}

// ---------------- pass 1c: scatter packed edges into bucket regions ----------------
__global__ void scatter_kernel(const int* __restrict__ dst,
                               const float* __restrict__ val,
                               const int* __restrict__ hist,
                               const int* __restrict__ bases,
                               unsigned* __restrict__ pairs, int n_e) {
    __shared__ int cur[NBUCKETS];
    for (int i = threadIdx.x; i < NBUCKETS; i += blockDim.x)
        cur[i] = bases[i] + hist[(size_t)i * gridDim.x + blockIdx.x];
    __syncthreads();
    const int span = (((n_e + (int)gridDim.x - 1) / (int)gridDim.x) + 3) & ~3;
    const int lo = blockIdx.x * span;
    const int hi = min(lo + span, n_e);
    const iv4* __restrict__ d4 = (const iv4*)dst;
    const fv4* __restrict__ v4 = (const fv4*)val;
    for (int j = (lo >> 2) + (int)threadIdx.x; j < (hi >> 2); j += blockDim.x) {
        iv4 d = d4[j];
        fv4 v = v4[j];
        { int p = atomicAdd(&cur[d.x >> VB_SHIFT], 1); pairs[p] = pack_edge(d.x, v.x); }
        { int p = atomicAdd(&cur[d.y >> VB_SHIFT], 1); pairs[p] = pack_edge(d.y, v.y); }
        { int p = atomicAdd(&cur[d.z >> VB_SHIFT], 1); pairs[p] = pack_edge(d.z, v.z); }
        { int p = atomicAdd(&cur[d.w >> VB_SHIFT], 1); pairs[p] = pack_edge(d.w, v.w); }
    }
    for (int j = max(lo, (hi >> 2) << 2) + (int)threadIdx.x; j < hi; j += blockDim.x) {
        int d = dst[j];
        int p = atomicAdd(&cur[d >> VB_SHIFT], 1);
        pairs[p] = pack_edge(d, val[j]);
    }
}

// ---------------- pass 2: per-bucket LDS reduction ----------------
__global__ void __launch_bounds__(1024)
bucket_reduce(const unsigned* __restrict__ pairs,
              const int* __restrict__ bases,
              const float* __restrict__ va,
              float* __restrict__ cbar,
              float* __restrict__ out,
              int n_v, int first_chunk, int last_chunk) {
    __shared__ float acc[VB];
    const int b = blockIdx.x;
    for (int i = threadIdx.x; i < VB; i += blockDim.x) acc[i] = 0.f;
    __syncthreads();
    const int start = bases[b], end = bases[b + 1];
    for (int j = start + (int)threadIdx.x; j < end; j += blockDim.x) {
        unsigned p = pairs[j];
        atomicAdd(&acc[p & (VB - 1)], __uint_as_float(p & 0xFFFFF800u));
    }
    __syncthreads();
    const int vbase = b << VB_SHIFT;
    for (int i = threadIdx.x; i < VB; i += blockDim.x) {
        int v = vbase + i;
        if (v >= n_v) break;
        float c = acc[i];
        if (!first_chunk) c += cbar[v];
        if (!last_chunk) {
            cbar[v] = c;
        } else {
            float2 a = ((const float2*)va)[v];
            float2 o; o.x = a.x; o.y = a.x * c;
            ((float2*)out)[v] = o;
        }
    }
}

// ---------------- fallback: device atomics (small ws / odd alignment) ----------------
__global__ void scatter_add_dev(const int* __restrict__ dst,
                                const float* __restrict__ w,
                                float* __restrict__ cbar, int n_e) {
    const int tid = blockIdx.x * blockDim.x + threadIdx.x;
    const int stride = gridDim.x * blockDim.x;
    for (int j = tid; j < n_e; j += stride)
        atomicAdd(&cbar[dst[j]], w[j]);
}

__global__ void finalize_single(const float* __restrict__ va,
                                const float* __restrict__ cbar,
                                float* __restrict__ out, int n_v) {
    const int tid = blockIdx.x * blockDim.x + threadIdx.x;
    const int stride = gridDim.x * blockDim.x;
    for (int i = tid; i < n_v; i += stride) {
        float bb = va[2 * i];
        float2 o; o.x = bb; o.y = bb * cbar[i];
        ((float2*)out)[i] = o;
    }
}

extern "C" void kernel_launch(void* const* d_in, const int* in_sizes, int n_in,
                              void* d_out, int out_size, void* d_ws, size_t ws_size,
                              hipStream_t stream) {
    const float* vertex_attr = (const float*)d_in[0];   // (n_v, 2) f32
    const int*   edgeij      = (const int*)d_in[1];     // (2, n_e) int32
    const float* edge_attr   = (const float*)d_in[2];   // (n_e, 1) f32

    const int n_vertices = in_sizes[0] / 2;
    const int n_edges    = in_sizes[2];
    const int* dst = edgeij + n_edges;                  // row 1 of (2, n_e)

    // workspace layout: [cbar n_v f32][hist NBUCKETS*NB_HIST][rowtot NBUCKETS]
    //                   [bases NBUCKETS+1][pad][pairs ...]
    char* base = (char*)d_ws;
    size_t off = 0;
    float* cbar = (float*)(base + off); off += (size_t)n_vertices * 4;
    int* hist   = (int*)(base + off);   off += (size_t)NBUCKETS * NB_HIST * 4;
    int* rowtot = (int*)(base + off);   off += (size_t)NBUCKETS * 4;
    int* bases  = (int*)(base + off);   off += (size_t)(NBUCKETS + 1) * 4;
    off = (off + 15) & ~(size_t)15;
    unsigned* pairs = (unsigned*)(base + off);

    const bool aligned16 = (((uintptr_t)dst & 15) == 0) && (((uintptr_t)edge_attr & 15) == 0);
    const bool fits = (n_vertices <= NBUCKETS * VB) && (ws_size > off + 4u * 4096u) && aligned16;

    if (fits) {
        size_t cap = (ws_size - off) / 4;               // packed edges that fit
        cap &= ~(size_t)3;
        int e0 = 0;
        bool first = true;
        while (e0 < n_edges) {
            int ec = (int)min((size_t)(n_edges - e0), cap);
            if (e0 + ec < n_edges) ec &= ~3;            // keep chunks 16B-aligned
            const int* dch = dst + e0;
            const float* vch = edge_attr + e0;
            const bool last = (e0 + ec >= n_edges);

            hist_kernel   <<<NB_HIST, TPB_BIN, 0, stream>>>(dch, hist, ec);
            scan_rows     <<<NBUCKETS, NB_HIST, 0, stream>>>(hist, rowtot);
            scan_bases    <<<1, NBUCKETS, 0, stream>>>(rowtot, bases);
            scatter_kernel<<<NB_HIST, TPB_BIN, 0, stream>>>(dch, vch, hist, bases, pairs, ec);
            bucket_reduce <<<NBUCKETS, 1024, 0, stream>>>(pairs, bases, vertex_attr, cbar,
                                                          (float*)d_out, n_vertices,
                                                          first ? 1 : 0, last ? 1 : 0);
            first = false;
            e0 += ec;
        }
    } else {
        // slow-but-correct fallback
        (void)hipMemsetAsync(cbar, 0, (size_t)n_vertices * 4, stream);
        int threads = 256;
        int blocks = (n_edges + threads - 1) / threads;
        if (blocks > 4096) blocks = 4096;
        scatter_add_dev<<<blocks, threads, 0, stream>>>(dst, edge_attr, cbar, n_edges);
        int fblocks = (n_vertices + threads - 1) / threads;
        if (fblocks > 2048) fblocks = 2048;
        finalize_single<<<fblocks, threads, 0, stream>>>(vertex_attr, cbar,
                                                         (float*)d_out, n_vertices);
    }
}

// Round 5
// 502.208 us; speedup vs baseline: 3.0885x; 1.1923x over previous
//
#include <hip/hip_runtime.h>

// out[i*2+0] = vertex_attr[i*2+0]
// out[i*2+1] = vertex_attr[i*2+0] * segment_sum(edge_attr, dst)[i]
//
// Round-3 lesson: f32 global atomics (any scope) run memory-side at ~1/cyc/XCD
//   -> never issue per-edge global atomics.
// Round-4 lesson: random 4B bucket-append writes amplify 4.8x in WRITE_SIZE
//   -> block-local counting sort in LDS, then write each bucket run
//      CONTIGUOUSLY so L2 write-combines full lines.
//
// Pipeline: hist (per-block bucket histogram) -> scans (deterministic layout)
//           -> scatter_sorted (LDS counting sort, coalesced bucket append)
//           -> bucket_reduce (one WG per 2048-vertex bucket, ds_add_f32,
//              exclusive plain-store finalize).
// Edge record packed to ONE u32: f32 val rounded to 21-bit mantissa (rel err
// 2^-12, absmax threshold 1.42) | 11-bit in-bucket vertex index.

#define VB_SHIFT 11
#define VB       (1 << VB_SHIFT)   // 2048 vertices per bucket
#define NBUCKETS 512               // covers up to 1,048,576 vertices
#define NB_HIST  512               // blocks in hist/scatter (== scan width)
#define TPB_BIN  512               // MUST equal NBUCKETS (scan code assumes)
#define TILE     4096              // edges per LDS counting-sort tile

typedef int   iv4 __attribute__((ext_vector_type(4)));
typedef float fv4 __attribute__((ext_vector_type(4)));

__device__ __forceinline__ unsigned pack_edge(int d, float v) {
    unsigned vb = __float_as_uint(v);
    vb = (vb + 0x400u) & 0xFFFFF800u;          // round mantissa to 21 bits
    return vb | (unsigned)(d & (VB - 1));
}

// ---------------- pass 1a: per-block bucket histogram ----------------
__global__ void __launch_bounds__(TPB_BIN)
hist_kernel(const int* __restrict__ dst, int* __restrict__ hist, int n_e) {
    __shared__ int h[NBUCKETS];
    for (int i = threadIdx.x; i < NBUCKETS; i += blockDim.x) h[i] = 0;
    __syncthreads();
    const int span = (((n_e + (int)gridDim.x - 1) / (int)gridDim.x) + 3) & ~3;
    const int lo = blockIdx.x * span;
    const int hi = min(lo + span, n_e);
    const iv4* __restrict__ d4 = (const iv4*)dst;
    for (int j = (lo >> 2) + (int)threadIdx.x; j < (hi >> 2); j += blockDim.x) {
        iv4 d = d4[j];
        atomicAdd(&h[d.x >> VB_SHIFT], 1);
        atomicAdd(&h[d.y >> VB_SHIFT], 1);
        atomicAdd(&h[d.z >> VB_SHIFT], 1);
        atomicAdd(&h[d.w >> VB_SHIFT], 1);
    }
    for (int j = max(lo, (hi >> 2) << 2) + (int)threadIdx.x; j < hi; j += blockDim.x)
        atomicAdd(&h[dst[j] >> VB_SHIFT], 1);
    __syncthreads();
    for (int i = threadIdx.x; i < NBUCKETS; i += blockDim.x)
        hist[(size_t)i * gridDim.x + blockIdx.x] = h[i];
}

// ---------------- pass 1b: scans ----------------
__global__ void scan_rows(int* __restrict__ hist, int* __restrict__ rowtot) {
    __shared__ int s[NB_HIST];
    const int r = blockIdx.x, t = threadIdx.x;
    int* row = hist + (size_t)r * NB_HIST;
    int x = row[t];
    s[t] = x;
    __syncthreads();
    for (int off = 1; off < NB_HIST; off <<= 1) {
        int add = (t >= off) ? s[t - off] : 0;
        __syncthreads();
        s[t] += add;
        __syncthreads();
    }
    row[t] = s[t] - x;                         // exclusive within row
    if (t == NB_HIST - 1) rowtot[r] = s[t];
}

__global__ void scan_bases(const int* __restrict__ rowtot, int* __restrict__ bases) {
    __shared__ int s[NBUCKETS];
    const int t = threadIdx.x;
    int x = rowtot[t];
    s[t] = x;
    __syncthreads();
    for (int off = 1; off < NBUCKETS; off <<= 1) {
        int add = (t >= off) ? s[t - off] : 0;
        __syncthreads();
        s[t] += add;
        __syncthreads();
    }
    bases[t] = s[t] - x;
    if (t == NBUCKETS - 1) bases[NBUCKETS] = s[t];
}

// ------- pass 1c: LDS counting-sort scatter (coalesced bucket append) -------
__global__ void __launch_bounds__(TPB_BIN)
scatter_sorted(const int* __restrict__ dst,
               const float* __restrict__ val,
               const int* __restrict__ hist,
               const int* __restrict__ bases,
               unsigned* __restrict__ pairs, int n_e) {
    __shared__ int cur[NBUCKETS];     // global cursor per bucket (this block)
    __shared__ int cnt[NBUCKETS];     // per-tile bucket counts
    __shared__ int loff[NBUCKETS];    // exclusive scan of cnt
    __shared__ int alloc[NBUCKETS];   // runtime placement cursors
    __shared__ unsigned sorted[TILE];
    __shared__ unsigned short bkt[TILE];

    const int t = threadIdx.x;        // TPB_BIN == NBUCKETS
    cur[t] = bases[t] + hist[(size_t)t * gridDim.x + blockIdx.x];
    __syncthreads();

    const int span = (((n_e + (int)gridDim.x - 1) / (int)gridDim.x) + 3) & ~3;
    const int lo = blockIdx.x * span;
    const int hi = min(lo + span, n_e);

    for (int t0 = lo; t0 < hi; t0 += TILE) {
        const int tn = min(TILE, hi - t0);
        cnt[t] = 0;
        __syncthreads();
        // count
        for (int j = t0 + t; j < t0 + tn; j += TPB_BIN)
            atomicAdd(&cnt[dst[j] >> VB_SHIFT], 1);
        __syncthreads();
        // exclusive scan cnt -> loff (Hillis-Steele, width 512)
        int x = cnt[t];
        loff[t] = x;
        __syncthreads();
        for (int off = 1; off < NBUCKETS; off <<= 1) {
            int add = (t >= off) ? loff[t - off] : 0;
            __syncthreads();
            loff[t] += add;
            __syncthreads();
        }
        int excl = loff[t] - x;       // own element only -> no race
        loff[t] = excl;
        alloc[t] = excl;
        __syncthreads();
        // place into sorted tile
        for (int j = t0 + t; j < t0 + tn; j += TPB_BIN) {
            int d = dst[j];
            int b = d >> VB_SHIFT;
            int pos = atomicAdd(&alloc[b], 1);
            sorted[pos] = pack_edge(d, val[j]);
            bkt[pos] = (unsigned short)b;
        }
        __syncthreads();
        // coalesced write: consecutive i within a bucket run -> consecutive
        // global addresses; same block streams sequential addrs per region.
        for (int i = t; i < tn; i += TPB_BIN) {
            int b = bkt[i];
            pairs[cur[b] + (i - loff[b])] = sorted[i];
        }
        __syncthreads();
        cur[t] += cnt[t];
        __syncthreads();
    }
}

// ---------------- pass 2: per-bucket LDS reduction ----------------
__global__ void __launch_bounds__(1024)
bucket_reduce(const unsigned* __restrict__ pairs,
              const int* __restrict__ bases,
              const float* __restrict__ va,
              float* __restrict__ cbar,
              float* __restrict__ out,
              int n_v, int first_chunk, int last_chunk) {
    __shared__ float acc[VB];
    const int b = blockIdx.x;
    for (int i = threadIdx.x; i < VB; i += blockDim.x) acc[i] = 0.f;
    __syncthreads();
    const int start = bases[b], end = bases[b + 1];
    for (int j = start + (int)threadIdx.x; j < end; j += blockDim.x) {
        unsigned p = pairs[j];
        atomicAdd(&acc[p & (VB - 1)], __uint_as_float(p & 0xFFFFF800u));
    }
    __syncthreads();
    const int vbase = b << VB_SHIFT;
    for (int i = threadIdx.x; i < VB; i += blockDim.x) {
        int v = vbase + i;
        if (v >= n_v) break;
        float c = acc[i];
        if (!first_chunk) c += cbar[v];
        if (!last_chunk) {
            cbar[v] = c;
        } else {
            float2 a = ((const float2*)va)[v];
            float2 o; o.x = a.x; o.y = a.x * c;
            ((float2*)out)[v] = o;
        }
    }
}

// ---------------- fallback: device atomics (small ws / odd alignment) -------
__global__ void scatter_add_dev(const int* __restrict__ dst,
                                const float* __restrict__ w,
                                float* __restrict__ cbar, int n_e) {
    const int tid = blockIdx.x * blockDim.x + threadIdx.x;
    const int stride = gridDim.x * blockDim.x;
    for (int j = tid; j < n_e; j += stride)
        atomicAdd(&cbar[dst[j]], w[j]);
}

__global__ void finalize_single(const float* __restrict__ va,
                                const float* __restrict__ cbar,
                                float* __restrict__ out, int n_v) {
    const int tid = blockIdx.x * blockDim.x + threadIdx.x;
    const int stride = gridDim.x * blockDim.x;
    for (int i = tid; i < n_v; i += stride) {
        float bb = va[2 * i];
        float2 o; o.x = bb; o.y = bb * cbar[i];
        ((float2*)out)[i] = o;
    }
}

extern "C" void kernel_launch(void* const* d_in, const int* in_sizes, int n_in,
                              void* d_out, int out_size, void* d_ws, size_t ws_size,
                              hipStream_t stream) {
    const float* vertex_attr = (const float*)d_in[0];   // (n_v, 2) f32
    const int*   edgeij      = (const int*)d_in[1];     // (2, n_e) int32
    const float* edge_attr   = (const float*)d_in[2];   // (n_e, 1) f32

    const int n_vertices = in_sizes[0] / 2;
    const int n_edges    = in_sizes[2];
    const int* dst = edgeij + n_edges;                  // row 1 of (2, n_e)

    // workspace layout: [cbar n_v f32][hist NBUCKETS*NB_HIST][rowtot NBUCKETS]
    //                   [bases NBUCKETS+1][pad][pairs ...]
    char* base = (char*)d_ws;
    size_t off = 0;
    float* cbar = (float*)(base + off); off += (size_t)n_vertices * 4;
    int* hist   = (int*)(base + off);   off += (size_t)NBUCKETS * NB_HIST * 4;
    int* rowtot = (int*)(base + off);   off += (size_t)NBUCKETS * 4;
    int* bases  = (int*)(base + off);   off += (size_t)(NBUCKETS + 1) * 4;
    off = (off + 15) & ~(size_t)15;
    unsigned* pairs = (unsigned*)(base + off);

    const bool aligned16 = (((uintptr_t)dst & 15) == 0) && (((uintptr_t)edge_attr & 15) == 0);
    const bool fits = (n_vertices <= NBUCKETS * VB) && (ws_size > off + 4u * 4096u) && aligned16;

    if (fits) {
        size_t cap = (ws_size - off) / 4;               // packed edges that fit
        cap &= ~(size_t)3;
        int e0 = 0;
        bool first = true;
        while (e0 < n_edges) {
            int ec = (int)min((size_t)(n_edges - e0), cap);
            if (e0 + ec < n_edges) ec &= ~3;            // keep chunks 16B-aligned
            const int* dch = dst + e0;
            const float* vch = edge_attr + e0;
            const bool last = (e0 + ec >= n_edges);

            hist_kernel   <<<NB_HIST, TPB_BIN, 0, stream>>>(dch, hist, ec);
            scan_rows     <<<NBUCKETS, NB_HIST, 0, stream>>>(hist, rowtot);
            scan_bases    <<<1, NBUCKETS, 0, stream>>>(rowtot, bases);
            scatter_sorted<<<NB_HIST, TPB_BIN, 0, stream>>>(dch, vch, hist, bases, pairs, ec);
            bucket_reduce <<<NBUCKETS, 1024, 0, stream>>>(pairs, bases, vertex_attr, cbar,
                                                          (float*)d_out, n_vertices,
                                                          first ? 1 : 0, last ? 1 : 0);
            first = false;
            e0 += ec;
        }
    } else {
        // slow-but-correct fallback
        (void)hipMemsetAsync(cbar, 0, (size_t)n_vertices * 4, stream);
        int threads = 256;
        int blocks = (n_edges + threads - 1) / threads;
        if (blocks > 4096) blocks = 4096;
        scatter_add_dev<<<blocks, threads, 0, stream>>>(dst, edge_attr, cbar, n_edges);
        int fblocks = (n_vertices + threads - 1) / threads;
        if (fblocks > 2048) fblocks = 2048;
        finalize_single<<<fblocks, threads, 0, stream>>>(vertex_attr, cbar,
                                                         (float*)d_out, n_vertices);
    }
}

// Round 6
// 324.158 us; speedup vs baseline: 4.7850x; 1.5493x over previous
//
#include <hip/hip_runtime.h>

// out[i*2+0] = vertex_attr[i*2+0]
// out[i*2+1] = vertex_attr[i*2+0] * segment_sum(edge_attr, dst)[i]
//
// Round-3 lesson: f32 global atomics (any scope) run memory-side ~1/cyc/XCD
//   -> never issue per-edge global atomics.
// Round-4 lesson: random 4B bucket appends amplify writes 4.8x -> sort in LDS.
// Round-5 lesson: 512-bucket LDS sort is barrier/scan-bound (24 barriers/tile,
//   runs of 8 still amplify 1.8x) -> 128 buckets, wave-shfl scan (~3 barriers
//   per tile), TILE=8192 (runs of 64 -> fully coalesced bucket appends).
//
// Edge record packed to ONE u32: f32 val rounded to 10-bit mantissa
// (rel err 2^-11; absmax threshold is 1.42) | 13-bit in-bucket vertex index.

#define VB_SHIFT 13
#define VB       (1 << VB_SHIFT)   // 8192 vertices per bucket
#define NBUCKETS 128               // 128 * 8192 = 1,048,576 vertices max
#define NB       1024              // hist/scatter grid (== scan_rows width)
#define TPB      512
#define TILE     8192              // edges per LDS sort tile
#define RSLICES  4                 // reduce blocks per bucket
#define RTPB     512

typedef int   iv4 __attribute__((ext_vector_type(4)));
typedef float fv4 __attribute__((ext_vector_type(4)));

__device__ __forceinline__ unsigned pack_edge(int d, float v) {
    unsigned vb = __float_as_uint(v);
    vb = (vb + 0x1000u) & 0xFFFFE000u;         // round-to-nearest, 10-bit mantissa
    return vb | (unsigned)(d & (VB - 1));
}

// ---------------- pass 1a: per-block bucket histogram ----------------
__global__ void __launch_bounds__(TPB)
hist_kernel(const int* __restrict__ dst, int* __restrict__ hist, int n_e) {
    __shared__ int h[NBUCKETS];
    const int t = threadIdx.x;
    if (t < NBUCKETS) h[t] = 0;
    __syncthreads();
    const int span = (((n_e + (int)gridDim.x - 1) / (int)gridDim.x) + 3) & ~3;
    const int lo = min((int)blockIdx.x * span, n_e);
    const int hi = min(lo + span, n_e);
    const int n4 = (hi - lo) >> 2;
    const iv4* __restrict__ d4 = (const iv4*)(dst + lo);
    for (int j = t; j < n4; j += TPB) {
        iv4 d = d4[j];
        atomicAdd(&h[d.x >> VB_SHIFT], 1);
        atomicAdd(&h[d.y >> VB_SHIFT], 1);
        atomicAdd(&h[d.z >> VB_SHIFT], 1);
        atomicAdd(&h[d.w >> VB_SHIFT], 1);
    }
    for (int j = lo + (n4 << 2) + t; j < hi; j += TPB)
        atomicAdd(&h[dst[j] >> VB_SHIFT], 1);
    __syncthreads();
    if (t < NBUCKETS) hist[(size_t)t * gridDim.x + blockIdx.x] = h[t];
}

// ---------------- pass 1b: scans (deterministic disjoint layout) ------------
__global__ void __launch_bounds__(NB)
scan_rows(int* __restrict__ hist, int* __restrict__ rowtot) {
    __shared__ int s[NB];
    const int r = blockIdx.x, t = threadIdx.x;
    int* row = hist + (size_t)r * NB;
    int x = row[t];
    s[t] = x;
    __syncthreads();
    for (int off = 1; off < NB; off <<= 1) {
        int add = (t >= off) ? s[t - off] : 0;
        __syncthreads();
        s[t] += add;
        __syncthreads();
    }
    row[t] = s[t] - x;                         // exclusive within row
    if (t == NB - 1) rowtot[r] = s[t];
}

__global__ void scan_bases(const int* __restrict__ rowtot, int* __restrict__ bases) {
    __shared__ int s[NBUCKETS];
    const int t = threadIdx.x;
    int x = rowtot[t];
    s[t] = x;
    __syncthreads();
    for (int off = 1; off < NBUCKETS; off <<= 1) {
        int add = (t >= off) ? s[t - off] : 0;
        __syncthreads();
        s[t] += add;
        __syncthreads();
    }
    bases[t] = s[t] - x;
    if (t == NBUCKETS - 1) bases[NBUCKETS] = s[t];
}

// ------- pass 1c: LDS counting-sort scatter, wave-shfl scan, runs of ~64 ----
__global__ void __launch_bounds__(TPB)
scatter_sorted(const int* __restrict__ dst,
               const float* __restrict__ val,
               const int* __restrict__ hist,
               const int* __restrict__ bases,
               unsigned* __restrict__ pairs, int n_e) {
    __shared__ int cur[NBUCKETS];     // global cursor per bucket (this block)
    __shared__ int cnt[NBUCKETS];
    __shared__ int loff[NBUCKETS];
    __shared__ int aloc[NBUCKETS];
    __shared__ int wsum;              // wave-0 total for cross-wave scan fixup
    __shared__ unsigned sorted[TILE];
    __shared__ unsigned char bkt[TILE];

    const int t = threadIdx.x;
    if (t < NBUCKETS) cur[t] = bases[t] + hist[(size_t)t * gridDim.x + blockIdx.x];

    const int span = (((n_e + (int)gridDim.x - 1) / (int)gridDim.x) + 3) & ~3;
    const int lo = min((int)blockIdx.x * span, n_e);
    const int hi = min(lo + span, n_e);

    for (int t0 = lo; t0 < hi; t0 += TILE) {
        const int tn = min(TILE, hi - t0);
        if (t < NBUCKETS) cnt[t] = 0;
        __syncthreads();
        const int n4 = tn >> 2;
        const iv4* __restrict__ d4 = (const iv4*)(dst + t0);
        const fv4* __restrict__ v4 = (const fv4*)(val + t0);
        // count
        for (int j = t; j < n4; j += TPB) {
            iv4 d = d4[j];
            atomicAdd(&cnt[d.x >> VB_SHIFT], 1);
            atomicAdd(&cnt[d.y >> VB_SHIFT], 1);
            atomicAdd(&cnt[d.z >> VB_SHIFT], 1);
            atomicAdd(&cnt[d.w >> VB_SHIFT], 1);
        }
        for (int j = (n4 << 2) + t; j < tn; j += TPB)
            atomicAdd(&cnt[dst[t0 + j] >> VB_SHIFT], 1);
        __syncthreads();
        // exclusive scan of cnt[128]: two full waves, shfl_up within wave
        int x = 0, incl = 0;
        if (t < NBUCKETS) {
            x = cnt[t];
            incl = x;
            #pragma unroll
            for (int off = 1; off < 64; off <<= 1) {
                int y = __shfl_up(incl, off, 64);
                if ((t & 63) >= off) incl += y;
            }
            if (t == 63) wsum = incl;
        }
        __syncthreads();
        if (t < NBUCKETS) {
            int e = incl - x + ((t >= 64) ? wsum : 0);
            loff[t] = e;
            aloc[t] = e;
        }
        __syncthreads();
        // place into sorted tile
        for (int j = t; j < n4; j += TPB) {
            iv4 d = d4[j];
            fv4 v = v4[j];
            { int b = d.x >> VB_SHIFT; int p = atomicAdd(&aloc[b], 1);
              sorted[p] = pack_edge(d.x, v.x); bkt[p] = (unsigned char)b; }
            { int b = d.y >> VB_SHIFT; int p = atomicAdd(&aloc[b], 1);
              sorted[p] = pack_edge(d.y, v.y); bkt[p] = (unsigned char)b; }
            { int b = d.z >> VB_SHIFT; int p = atomicAdd(&aloc[b], 1);
              sorted[p] = pack_edge(d.z, v.z); bkt[p] = (unsigned char)b; }
            { int b = d.w >> VB_SHIFT; int p = atomicAdd(&aloc[b], 1);
              sorted[p] = pack_edge(d.w, v.w); bkt[p] = (unsigned char)b; }
        }
        for (int j = (n4 << 2) + t; j < tn; j += TPB) {
            int d = dst[t0 + j];
            int b = d >> VB_SHIFT;
            int p = atomicAdd(&aloc[b], 1);
            sorted[p] = pack_edge(d, val[t0 + j]);
            bkt[p] = (unsigned char)b;
        }
        __syncthreads();
        // coalesced write-out: runs of ~tn/128 = 64 consecutive addresses
        for (int i = t; i < tn; i += TPB) {
            int b = bkt[i];
            pairs[cur[b] + (i - loff[b])] = sorted[i];
        }
        __syncthreads();
        if (t < NBUCKETS) cur[t] += cnt[t];
        __syncthreads();                       // protect cnt before next zero
    }
}

// ---------------- pass 2: per-(bucket,slice) LDS reduction ------------------
__global__ void __launch_bounds__(RTPB)
bucket_reduce(const unsigned* __restrict__ pairs,
              const int* __restrict__ bases,
              float* __restrict__ partial) {   // [NBUCKETS][RSLICES][VB], +=
    __shared__ float acc[VB];                  // 32 KB
    const int b = blockIdx.x / RSLICES;
    const int s = blockIdx.x % RSLICES;
    const int t = threadIdx.x;
    float* pp = partial + ((size_t)b * RSLICES + s) * VB;
    for (int i = t; i < VB; i += RTPB) acc[i] = pp[i];   // accumulate chunks
    __syncthreads();
    const int start = bases[b], end = bases[b + 1];
    const int len = end - start;
    const int per = (len + RSLICES - 1) / RSLICES;
    const int j0 = start + s * per;
    const int j1 = min(j0 + per, end);
    for (int j = j0 + t; j < j1; j += RTPB) {
        unsigned p = pairs[j];
        atomicAdd(&acc[p & (VB - 1)], __uint_as_float(p & 0xFFFFE000u));
    }
    __syncthreads();
    for (int i = t; i < VB; i += RTPB) pp[i] = acc[i];
}

// ---------------- pass 3: combine slices + write output ---------------------
__global__ void __launch_bounds__(TPB)
combine_out(const float* __restrict__ partial, const float* __restrict__ va,
            float* __restrict__ out, int n_v) {
    const int tid = blockIdx.x * blockDim.x + threadIdx.x;
    const int stride = gridDim.x * blockDim.x;
    const int n_q = n_v >> 2;
    for (int q = tid; q < n_q; q += stride) {
        int v = q << 2;
        int b = v >> VB_SHIFT;
        int idx = v & (VB - 1);
        const float* pb = partial + (size_t)b * RSLICES * VB + idx;
        fv4 c = (fv4){0.f, 0.f, 0.f, 0.f};
        #pragma unroll
        for (int s = 0; s < RSLICES; ++s)
            c += *(const fv4*)(pb + (size_t)s * VB);
        fv4 a0 = ((const fv4*)va)[2 * q];      // b0 ~ b1 ~
        fv4 a1 = ((const fv4*)va)[2 * q + 1];  // b2 ~ b3 ~
        fv4 o0 = (fv4){a0.x, a0.x * c.x, a0.z, a0.z * c.y};
        fv4 o1 = (fv4){a1.x, a1.x * c.z, a1.z, a1.z * c.w};
        ((fv4*)out)[2 * q]     = o0;
        ((fv4*)out)[2 * q + 1] = o1;
    }
    for (int v = (n_q << 2) + tid; v < n_v; v += stride) {
        int b = v >> VB_SHIFT;
        int idx = v & (VB - 1);
        float c = 0.f;
        for (int s = 0; s < RSLICES; ++s)
            c += partial[((size_t)b * RSLICES + s) * VB + idx];
        float bb = va[2 * v];
        out[2 * v] = bb;
        out[2 * v + 1] = bb * c;
    }
}

// ---------------- fallback: device atomics (small ws / odd alignment) -------
__global__ void scatter_add_dev(const int* __restrict__ dst,
                                const float* __restrict__ w,
                                float* __restrict__ cbar, int n_e) {
    const int tid = blockIdx.x * blockDim.x + threadIdx.x;
    const int stride = gridDim.x * blockDim.x;
    for (int j = tid; j < n_e; j += stride)
        atomicAdd(&cbar[dst[j]], w[j]);
}

__global__ void finalize_single(const float* __restrict__ va,
                                const float* __restrict__ cbar,
                                float* __restrict__ out, int n_v) {
    const int tid = blockIdx.x * blockDim.x + threadIdx.x;
    const int stride = gridDim.x * blockDim.x;
    for (int i = tid; i < n_v; i += stride) {
        float bb = va[2 * i];
        float2 o; o.x = bb; o.y = bb * cbar[i];
        ((float2*)out)[i] = o;
    }
}

extern "C" void kernel_launch(void* const* d_in, const int* in_sizes, int n_in,
                              void* d_out, int out_size, void* d_ws, size_t ws_size,
                              hipStream_t stream) {
    const float* vertex_attr = (const float*)d_in[0];   // (n_v, 2) f32
    const int*   edgeij      = (const int*)d_in[1];     // (2, n_e) int32
    const float* edge_attr   = (const float*)d_in[2];   // (n_e, 1) f32

    const int n_vertices = in_sizes[0] / 2;
    const int n_edges    = in_sizes[2];
    const int* dst = edgeij + n_edges;                  // row 1 of (2, n_e)

    // ws layout: [hist 128x1024][rowtot][bases][pad][partial 16MB][pairs ...]
    char* base = (char*)d_ws;
    size_t off = 0;
    int* hist   = (int*)(base + off); off += (size_t)NBUCKETS * NB * 4;
    int* rowtot = (int*)(base + off); off += (size_t)NBUCKETS * 4;
    int* bases  = (int*)(base + off); off += (size_t)(NBUCKETS + 1) * 4;
    off = (off + 255) & ~(size_t)255;
    const size_t partial_elems = (size_t)NBUCKETS * RSLICES * VB;
    float* partial = (float*)(base + off); off += partial_elems * 4;   // 16 MB
    unsigned* pairs = (unsigned*)(base + off);

    const bool aligned16 = (((uintptr_t)dst & 15) == 0) &&
                           (((uintptr_t)edge_attr & 15) == 0) &&
                           (((uintptr_t)partial & 15) == 0);
    const bool fits = (n_vertices <= NBUCKETS * VB) &&
                      (ws_size > off + (size_t)(4 << 20)) && aligned16;

    if (fits) {
        (void)hipMemsetAsync(partial, 0, partial_elems * 4, stream);
        size_t cap = (ws_size - off) / 4;               // packed edges that fit
        cap &= ~(size_t)3;
        int e0 = 0;
        while (e0 < n_edges) {
            int ec = (int)min((size_t)(n_edges - e0), cap);
            if (e0 + ec < n_edges) ec &= ~3;            // keep chunks 16B-aligned
            hist_kernel   <<<NB, TPB, 0, stream>>>(dst + e0, hist, ec);
            scan_rows     <<<NBUCKETS, NB, 0, stream>>>(hist, rowtot);
            scan_bases    <<<1, NBUCKETS, 0, stream>>>(rowtot, bases);
            scatter_sorted<<<NB, TPB, 0, stream>>>(dst + e0, edge_attr + e0,
                                                   hist, bases, pairs, ec);
            bucket_reduce <<<NBUCKETS * RSLICES, RTPB, 0, stream>>>(pairs, bases, partial);
            e0 += ec;
        }
        combine_out<<<512, TPB, 0, stream>>>(partial, vertex_attr,
                                             (float*)d_out, n_vertices);
    } else {
        // slow-but-correct fallback
        float* cbar = (float*)d_ws;
        (void)hipMemsetAsync(cbar, 0, (size_t)n_vertices * 4, stream);
        int threads = 256;
        int blocks = (n_edges + threads - 1) / threads;
        if (blocks > 4096) blocks = 4096;
        scatter_add_dev<<<blocks, threads, 0, stream>>>(dst, edge_attr, cbar, n_edges);
        int fblocks = (n_vertices + threads - 1) / threads;
        if (fblocks > 2048) fblocks = 2048;
        finalize_single<<<fblocks, threads, 0, stream>>>(vertex_attr, cbar,
                                                         (float*)d_out, n_vertices);
    }
}